// Round 3
// baseline (882.927 us; speedup 1.0000x reference)
//
#include <hip/hip_runtime.h>
#include <math.h>

typedef float  f32x4 __attribute__((ext_vector_type(4)));
typedef short  s16x8 __attribute__((ext_vector_type(8)));
typedef unsigned short u16;

#define DEVI static __device__ __forceinline__

constexpr int B_   = 32, N0_ = 513, C_ = 768, H_ = 12, T_ = 10;
constexpr int NSEQ = 523;                 // 1 + T + (N0-1)
constexpr int M_   = B_ * NSEQ;           // 16736
constexpr int HID_ = 3072;
constexpr float SCALE_ = 0.125f;          // 64^-0.5
constexpr int NPAD = 576;                 // 9*64, padded seq for vT tiles

// ---- workspace layout (bytes) ----
// h (bf16 activations, reused for h1/h2):      [0, 25706496)
// qkv bf16 [M,2304] (later reused as hmid,
//   hmid spills into the dead vT region):      [OFF_A, ...)
// vT bf16 [B*H][64][NPAD]:                     [OFF_VT, +28311552)
// o  bf16 [M,768]:                             [OFF_O, +25706496)
// weights bf16:                                [OFF_W, +14155776)
// total ~171 MB.  d_out doubles as xcat/x2 fp32 residual buffer.
constexpr size_t OFF_A  = 25706496;
constexpr size_t OFF_VT = OFF_A + 77119488;     // 102825984
constexpr size_t OFF_O  = OFF_VT + 28311552;    // 131137536
constexpr size_t OFF_W  = OFF_O + 25706496;     // 156844032
constexpr size_t OFF_WQ = OFF_W;
constexpr size_t OFF_WP = OFF_WQ + 3538944;
constexpr size_t OFF_W1 = OFF_WP + 1179648;
constexpr size_t OFF_W2 = OFF_W1 + 4718592;

DEVI u16 f2bf(float f) {                  // RNE f32 -> bf16 bits
  union { float f; unsigned u; } x; x.f = f;
  unsigned r = x.u + 0x7fffu + ((x.u >> 16) & 1u);
  return (u16)(r >> 16);
}

DEVI void async_ld16(const void* g, void* l) {
  __builtin_amdgcn_global_load_lds(
      (const __attribute__((address_space(1))) unsigned*)g,
      (__attribute__((address_space(3))) unsigned*)l, 16, 0, 0);
}

DEVI f32x4 mfma16(s16x8 a, s16x8 b, f32x4 c) {
  return __builtin_amdgcn_mfma_f32_16x16x32_bf16(a, b, c, 0, 0, 0);
}

// ---------------- weight f32 -> bf16 ----------------
__global__ void k_cvt(const float* __restrict__ in, u16* __restrict__ out, int n4) {
  int i = blockIdx.x * 256 + threadIdx.x;
  if (i >= n4) return;
  float4 v = reinterpret_cast<const float4*>(in)[i];
  ushort4 o;
  o.x = f2bf(v.x); o.y = f2bf(v.y); o.z = f2bf(v.z); o.w = f2bf(v.w);
  reinterpret_cast<ushort4*>(out)[i] = o;
}

// ---------------- concat + prompt fusion -> xcat (fp32, in d_out) ----------------
__global__ void k_build(const float* __restrict__ x, const float* __restrict__ gf,
                        const float* __restrict__ tp, const float* __restrict__ pe,
                        const float* __restrict__ s1, float* __restrict__ xcat) {
  int i = blockIdx.x * 256 + threadIdx.x;          // float4 index
  if (i >= M_ * C_ / 4) return;
  int row = i / (C_ / 4), c4 = i % (C_ / 4);
  int b = row / NSEQ, n = row - b * NSEQ;
  float4 v;
  if (n == 0) {
    v = reinterpret_cast<const float4*>(x + (size_t)b * N0_ * C_)[c4];
  } else if (n <= T_) {
    int t = n - 1;
    float4 a  = reinterpret_cast<const float4*>(pe + (size_t)t * C_)[c4];
    float4 tv = reinterpret_cast<const float4*>(tp + (size_t)t * C_)[c4];
    float4 g  = reinterpret_cast<const float4*>(gf + (size_t)b * C_)[c4];
    float s = s1[0];
    v.x = a.x + s * g.x + tv.x; v.y = a.y + s * g.y + tv.y;
    v.z = a.z + s * g.z + tv.z; v.w = a.w + s * g.w + tv.w;
  } else {
    v = reinterpret_cast<const float4*>(x + ((size_t)b * N0_ + (n - T_)) * C_)[c4];
  }
  reinterpret_cast<float4*>(xcat + (size_t)row * C_)[c4] = v;
}

// ---------------- LayerNorm (wave per row) -> bf16 ----------------
__global__ void k_ln(const float* __restrict__ xin, const float* __restrict__ g,
                     const float* __restrict__ bb, u16* __restrict__ hout) {
  int lane = threadIdx.x & 63, wid = threadIdx.x >> 6;
  int row = blockIdx.x * 4 + wid;
  const float4* xr = reinterpret_cast<const float4*>(xin + (size_t)row * C_);
  float4 v[3]; float s = 0.f, sq = 0.f;
#pragma unroll
  for (int c = 0; c < 3; ++c) {
    v[c] = xr[c * 64 + lane];
    s  += v[c].x + v[c].y + v[c].z + v[c].w;
    sq += v[c].x * v[c].x + v[c].y * v[c].y + v[c].z * v[c].z + v[c].w * v[c].w;
  }
#pragma unroll
  for (int m = 1; m < 64; m <<= 1) { s += __shfl_xor(s, m, 64); sq += __shfl_xor(sq, m, 64); }
  float mean = s * (1.f / C_);
  float rstd = rsqrtf(sq * (1.f / C_) - mean * mean + 1e-5f);
  ushort4* orow = reinterpret_cast<ushort4*>(hout + (size_t)row * C_);
#pragma unroll
  for (int c = 0; c < 3; ++c) {
    float4 gv = reinterpret_cast<const float4*>(g)[c * 64 + lane];
    float4 bv = reinterpret_cast<const float4*>(bb)[c * 64 + lane];
    ushort4 o;
    o.x = f2bf((v[c].x - mean) * rstd * gv.x + bv.x);
    o.y = f2bf((v[c].y - mean) * rstd * gv.y + bv.y);
    o.z = f2bf((v[c].z - mean) * rstd * gv.z + bv.z);
    o.w = f2bf((v[c].w - mean) * rstd * gv.w + bv.w);
    orow[c * 64 + lane] = o;
  }
}

// ---------------- GEMM: out[M,N] = A[M,K] * Bw[N,K]^T  (both row-major, K contig) ----
// 128x128 tile, BK=64, 4 waves (2x2), global_load_lds w=16, XOR-swizzled LDS.
// EPI 0: qkv   -> bf16 out + scattered vT copy for the V part
// EPI 1: +bias +resid -> fp32 out (proj and fc2)
// EPI 2: +bias, exact GELU -> bf16 out (fc1)
template<int EPI, int NDIM, int KDIM>
__global__ __launch_bounds__(256) void k_gemm(
    const u16* __restrict__ A, const u16* __restrict__ Bw,
    u16* __restrict__ outb, float* __restrict__ outf,
    const float* __restrict__ bias, const float* __restrict__ resid,
    u16* __restrict__ vT) {
  __shared__ __align__(16) char lds[32768];        // A tile 16K | B tile 16K
  const int m0 = blockIdx.x * 128, n0 = blockIdx.y * 128;
  const int lane = threadIdx.x & 63, wid = threadIdx.x >> 6;
  const int wr = wid >> 1, wc = wid & 1;
  f32x4 acc[4][4] = {};

  for (int k0 = 0; k0 < KDIM; k0 += 64) {
    __syncthreads();                               // protect LDS from prev-iter readers
#pragma unroll
    for (int jj = 0; jj < 4; ++jj) {               // stage A: 16 x 1KB instrs
      int j = wid * 4 + jj;
      int row = j * 8 + (lane >> 3);
      int gm = m0 + row; if (gm > M_ - 1) gm = M_ - 1;
      int cb = ((lane & 7) * 16) ^ ((row & 7) << 4);
      async_ld16((const char*)A + ((size_t)gm * KDIM + k0) * 2 + cb, lds + j * 1024);
    }
#pragma unroll
    for (int jj = 0; jj < 4; ++jj) {               // stage B
      int j = wid * 4 + jj;
      int row = j * 8 + (lane >> 3);
      int cb = ((lane & 7) * 16) ^ ((row & 7) << 4);
      async_ld16((const char*)Bw + ((size_t)(n0 + row) * KDIM + k0) * 2 + cb,
                 lds + 16384 + j * 1024);
    }
    __syncthreads();
#pragma unroll
    for (int kk = 0; kk < 2; ++kk) {
      s16x8 af[4], bfr[4];
#pragma unroll
      for (int i = 0; i < 4; ++i) {
        int row = wr * 64 + i * 16 + (lane & 15);
        int cb = (kk * 64 + (lane >> 4) * 16) ^ ((row & 7) << 4);
        af[i] = *reinterpret_cast<const s16x8*>(lds + row * 128 + cb);
      }
#pragma unroll
      for (int j = 0; j < 4; ++j) {
        int row = wc * 64 + j * 16 + (lane & 15);
        int cb = (kk * 64 + (lane >> 4) * 16) ^ ((row & 7) << 4);
        bfr[j] = *reinterpret_cast<const s16x8*>(lds + 16384 + row * 128 + cb);
      }
#pragma unroll
      for (int i = 0; i < 4; ++i)
#pragma unroll
        for (int j = 0; j < 4; ++j)
          acc[i][j] = mfma16(af[i], bfr[j], acc[i][j]);
    }
  }

  // epilogue: C/D layout col=lane&15, row=(lane>>4)*4+reg
#pragma unroll
  for (int i = 0; i < 4; ++i) {
#pragma unroll
    for (int j = 0; j < 4; ++j) {
#pragma unroll
      for (int r = 0; r < 4; ++r) {
        int gm = m0 + wr * 64 + i * 16 + (lane >> 4) * 4 + r;
        int gn = n0 + wc * 64 + j * 16 + (lane & 15);
        if (gm < M_) {
          float v = acc[i][j][r];
          if constexpr (EPI == 0) {
            u16 bv = f2bf(v);
            outb[(size_t)gm * NDIM + gn] = bv;
            if (gn >= 2 * C_) {                     // V part -> transposed copy
              int hh = (gn - 2 * C_) >> 6;
              int dh = gn & 63;
              int b2 = gm / NSEQ, nn = gm - b2 * NSEQ;
              vT[((size_t)(b2 * H_ + hh) * 64 + dh) * NPAD + nn] = bv;
            }
          } else if constexpr (EPI == 1) {
            size_t idx = (size_t)gm * NDIM + gn;
            outf[idx] = v + bias[gn] + resid[idx];
          } else {
            float t = v + bias[gn];
            outb[(size_t)gm * NDIM + gn] =
                f2bf(0.5f * t * (1.f + erff(t * 0.70710678118654752f)));
          }
        }
      }
    }
  }
}

// ---------------- flash attention ----------------
// block = (qtile of 64 rows) x (b,h); 4 waves, wave owns 16 q rows.
__global__ __launch_bounds__(256) void k_attn(const u16* __restrict__ qkv,
                                              const u16* __restrict__ vT,
                                              u16* __restrict__ o) {
  __shared__ __align__(16) char lds[24576];   // K 8K | Vt 8K | P 4x2K
  const int qt = blockIdx.x, bh = blockIdx.y;
  const int b = bh / H_, h = bh - b * H_;
  const int lane = threadIdx.x & 63, wid = threadIdx.x >> 6;

  s16x8 qf[2];
  {
    int n = qt * 64 + wid * 16 + (lane & 15); if (n > NSEQ - 1) n = NSEQ - 1;
    const u16* qrow = qkv + (size_t)(b * NSEQ + n) * (3 * C_) + h * 64 + (lane >> 4) * 8;
    qf[0] = *reinterpret_cast<const s16x8*>(qrow);
    qf[1] = *reinterpret_cast<const s16x8*>(qrow + 32);
  }
  float m_run[4] = {-1e30f, -1e30f, -1e30f, -1e30f};
  float l_run[4] = {0.f, 0.f, 0.f, 0.f};
  f32x4 oacc[4] = {};
  char* pl = lds + 16384 + wid * 2048;

  for (int t = 0; t < 9; ++t) {
    const int kv0 = t * 64;
    __syncthreads();
#pragma unroll
    for (int jj = 0; jj < 2; ++jj) {          // stage K tile [64 kv][64 dh]
      int j = wid * 2 + jj;
      int row = j * 8 + (lane >> 3);
      int n = kv0 + row; if (n > NSEQ - 1) n = NSEQ - 1;
      int cb = ((lane & 7) * 16) ^ ((row & 7) << 4);
      async_ld16((const char*)(qkv + (size_t)(b * NSEQ + n) * (3 * C_) + C_ + h * 64) + cb,
                 lds + j * 1024);
    }
#pragma unroll
    for (int jj = 0; jj < 2; ++jj) {          // stage Vt tile [64 dh][64 kv]
      int j = wid * 2 + jj;
      int dh = j * 8 + (lane >> 3);
      int cb = ((lane & 7) * 16) ^ ((dh & 7) << 4);
      async_ld16((const char*)(vT + ((size_t)bh * 64 + dh) * NPAD + kv0) + cb,
                 lds + 8192 + j * 1024);
    }
    __syncthreads();

    f32x4 sfr[4] = {};
#pragma unroll
    for (int kk = 0; kk < 2; ++kk) {
#pragma unroll
      for (int fc = 0; fc < 4; ++fc) {
        int row = fc * 16 + (lane & 15);
        int cb = (kk * 64 + (lane >> 4) * 16) ^ ((row & 7) << 4);
        s16x8 kf = *reinterpret_cast<const s16x8*>(lds + row * 128 + cb);
        sfr[fc] = mfma16(qf[kk], kf, sfr[fc]);
      }
    }
#pragma unroll
    for (int fc = 0; fc < 4; ++fc) {          // scale + tail mask BEFORE max
      bool valid = (kv0 + fc * 16 + (lane & 15)) < NSEQ;
#pragma unroll
      for (int r = 0; r < 4; ++r)
        sfr[fc][r] = valid ? sfr[fc][r] * SCALE_ : -1e30f;
    }
#pragma unroll
    for (int r = 0; r < 4; ++r) {             // online softmax per q row
      float mx = fmaxf(fmaxf(sfr[0][r], sfr[1][r]), fmaxf(sfr[2][r], sfr[3][r]));
      mx = fmaxf(mx, __shfl_xor(mx, 1, 64));
      mx = fmaxf(mx, __shfl_xor(mx, 2, 64));
      mx = fmaxf(mx, __shfl_xor(mx, 4, 64));
      mx = fmaxf(mx, __shfl_xor(mx, 8, 64));
      float mnew = fmaxf(m_run[r], mx);
      float sc = __expf(m_run[r] - mnew);
      l_run[r] *= sc;
#pragma unroll
      for (int f2 = 0; f2 < 4; ++f2) oacc[f2][r] *= sc;
      float ps = 0.f;
#pragma unroll
      for (int fc = 0; fc < 4; ++fc) {
        float p = __expf(sfr[fc][r] - mnew);
        sfr[fc][r] = p; ps += p;
      }
      ps += __shfl_xor(ps, 1, 64);
      ps += __shfl_xor(ps, 2, 64);
      ps += __shfl_xor(ps, 4, 64);
      ps += __shfl_xor(ps, 8, 64);
      l_run[r] += ps;
      m_run[r] = mnew;
    }
    // P: C/D layout -> per-wave LDS (swizzled) -> A-fragment layout
#pragma unroll
    for (int fc = 0; fc < 4; ++fc)
#pragma unroll
      for (int r = 0; r < 4; ++r) {
        int row = (lane >> 4) * 4 + r;
        int cb = ((fc * 16 + (lane & 15)) * 2) ^ ((row & 7) << 4);
        *reinterpret_cast<u16*>(pl + row * 128 + cb) = f2bf(sfr[fc][r]);
      }
    s16x8 pf[2];
#pragma unroll
    for (int ks = 0; ks < 2; ++ks) {
      int row = lane & 15;
      int cb = (ks * 64 + (lane >> 4) * 16) ^ ((row & 7) << 4);
      pf[ks] = *reinterpret_cast<const s16x8*>(pl + row * 128 + cb);
    }
#pragma unroll
    for (int f2 = 0; f2 < 4; ++f2)
#pragma unroll
      for (int ks = 0; ks < 2; ++ks) {
        int vrow = f2 * 16 + (lane & 15);
        int cb = (ks * 64 + (lane >> 4) * 16) ^ ((vrow & 7) << 4);
        s16x8 vf = *reinterpret_cast<const s16x8*>(lds + 8192 + vrow * 128 + cb);
        oacc[f2] = mfma16(pf[ks], vf, oacc[f2]);
      }
  }
#pragma unroll
  for (int f2 = 0; f2 < 4; ++f2)
#pragma unroll
    for (int r = 0; r < 4; ++r) {
      int n = qt * 64 + wid * 16 + (lane >> 4) * 4 + r;
      if (n < NSEQ) {
        float val = oacc[f2][r] / l_run[r];
        o[(size_t)(b * NSEQ + n) * C_ + h * 64 + f2 * 16 + (lane & 15)] = f2bf(val);
      }
    }
}

extern "C" void kernel_launch(void* const* d_in, const int* in_sizes, int n_in,
                              void* d_out, int out_size, void* d_ws, size_t ws_size,
                              hipStream_t stream) {
  const float* x    = (const float*)d_in[0];
  const float* gf   = (const float*)d_in[1];
  const float* tp   = (const float*)d_in[2];
  const float* pe   = (const float*)d_in[3];
  const float* s1   = (const float*)d_in[4];
  const float* g1   = (const float*)d_in[5];
  const float* b1   = (const float*)d_in[6];
  const float* wqkv = (const float*)d_in[7];
  const float* wproj= (const float*)d_in[8];
  const float* bproj= (const float*)d_in[9];
  const float* g2   = (const float*)d_in[10];
  const float* b2   = (const float*)d_in[11];
  const float* wfc1 = (const float*)d_in[12];
  const float* bfc1 = (const float*)d_in[13];
  const float* wfc2 = (const float*)d_in[14];
  const float* bfc2 = (const float*)d_in[15];

  char* ws = (char*)d_ws;
  u16* h    = (u16*)ws;
  u16* qkvb = (u16*)(ws + OFF_A);
  u16* hmid = qkvb;                       // reuse after attention (spills into dead vT)
  u16* vTb  = (u16*)(ws + OFF_VT);
  u16* ob   = (u16*)(ws + OFF_O);
  u16* wqb  = (u16*)(ws + OFF_WQ);
  u16* wpb  = (u16*)(ws + OFF_WP);
  u16* w1b  = (u16*)(ws + OFF_W1);
  u16* w2b  = (u16*)(ws + OFF_W2);
  float* xcat = (float*)d_out;            // fp32 residual lives in d_out

  k_cvt<<<(442368 + 255) / 256, 256, 0, stream>>>(wqkv, wqb, 442368);
  k_cvt<<<(147456 + 255) / 256, 256, 0, stream>>>(wproj, wpb, 147456);
  k_cvt<<<(589824 + 255) / 256, 256, 0, stream>>>(wfc1, w1b, 589824);
  k_cvt<<<(589824 + 255) / 256, 256, 0, stream>>>(wfc2, w2b, 589824);

  k_build<<<(M_ * C_ / 4 + 255) / 256, 256, 0, stream>>>(x, gf, tp, pe, s1, xcat);
  k_ln<<<M_ / 4, 256, 0, stream>>>(xcat, g1, b1, h);
  k_gemm<0, 2304, 768><<<dim3(131, 18), 256, 0, stream>>>(h, wqb, qkvb, nullptr, nullptr, nullptr, vTb);
  k_attn<<<dim3(9, B_ * H_), 256, 0, stream>>>(qkvb, vTb, ob);
  k_gemm<1, 768, 768><<<dim3(131, 6), 256, 0, stream>>>(ob, wpb, nullptr, xcat, bproj, xcat, nullptr);
  k_ln<<<M_ / 4, 256, 0, stream>>>(xcat, g2, b2, h);
  k_gemm<2, 3072, 768><<<dim3(131, 24), 256, 0, stream>>>(h, w1b, hmid, nullptr, bfc1, nullptr, nullptr);
  k_gemm<1, 768, 3072><<<dim3(131, 6), 256, 0, stream>>>(hmid, w2b, nullptr, (float*)d_out, bfc2, xcat, nullptr);
}

// Round 6
// 850.814 us; speedup vs baseline: 1.0377x; 1.0377x over previous
//
#include <hip/hip_runtime.h>
#include <math.h>

typedef float  f32x4 __attribute__((ext_vector_type(4)));
typedef short  s16x8 __attribute__((ext_vector_type(8)));
typedef unsigned short u16;

#define DEVI static __device__ __forceinline__

constexpr int B_   = 32, N0_ = 513, C_ = 768, H_ = 12, T_ = 10;
constexpr int NSEQ = 523;                 // 1 + T + (N0-1)
constexpr int M_   = B_ * NSEQ;           // 16736
constexpr int HID_ = 3072;
constexpr float SCALE_ = 0.125f;          // 64^-0.5
constexpr int NPAD = 576;                 // 9*64, padded seq for vT tiles

// ---- workspace layout (bytes) ----
constexpr size_t OFF_A  = 25706496;
constexpr size_t OFF_VT = OFF_A + 77119488;     // 102825984
constexpr size_t OFF_O  = OFF_VT + 28311552;    // 131137536
constexpr size_t OFF_W  = OFF_O + 25706496;     // 156844032
constexpr size_t OFF_WQ = OFF_W;
constexpr size_t OFF_WP = OFF_WQ + 3538944;
constexpr size_t OFF_W1 = OFF_WP + 1179648;
constexpr size_t OFF_W2 = OFF_W1 + 4718592;

DEVI u16 f2bf(float f) {                  // RNE f32 -> bf16 bits
  union { float f; unsigned u; } x; x.f = f;
  unsigned r = x.u + 0x7fffu + ((x.u >> 16) & 1u);
  return (u16)(r >> 16);
}

DEVI void async_ld16(const void* g, void* l) {
  __builtin_amdgcn_global_load_lds(
      (const __attribute__((address_space(1))) unsigned*)g,
      (__attribute__((address_space(3))) unsigned*)l, 16, 0, 0);
}

DEVI f32x4 mfma16(s16x8 a, s16x8 b, f32x4 c) {
  return __builtin_amdgcn_mfma_f32_16x16x32_bf16(a, b, c, 0, 0, 0);
}

// ---------------- weight f32 -> bf16 ----------------
__global__ void k_cvt(const float* __restrict__ in, u16* __restrict__ out, int n4) {
  int i = blockIdx.x * 256 + threadIdx.x;
  if (i >= n4) return;
  float4 v = reinterpret_cast<const float4*>(in)[i];
  ushort4 o;
  o.x = f2bf(v.x); o.y = f2bf(v.y); o.z = f2bf(v.z); o.w = f2bf(v.w);
  reinterpret_cast<ushort4*>(out)[i] = o;
}

// ---------------- concat + prompt fusion -> xcat (fp32, in d_out) ----------------
__global__ void k_build(const float* __restrict__ x, const float* __restrict__ gf,
                        const float* __restrict__ tp, const float* __restrict__ pe,
                        const float* __restrict__ s1, float* __restrict__ xcat) {
  int i = blockIdx.x * 256 + threadIdx.x;          // float4 index
  if (i >= M_ * C_ / 4) return;
  int row = i / (C_ / 4), c4 = i % (C_ / 4);
  int b = row / NSEQ, n = row - b * NSEQ;
  float4 v;
  if (n == 0) {
    v = reinterpret_cast<const float4*>(x + (size_t)b * N0_ * C_)[c4];
  } else if (n <= T_) {
    int t = n - 1;
    float4 a  = reinterpret_cast<const float4*>(pe + (size_t)t * C_)[c4];
    float4 tv = reinterpret_cast<const float4*>(tp + (size_t)t * C_)[c4];
    float4 g  = reinterpret_cast<const float4*>(gf + (size_t)b * C_)[c4];
    float s = s1[0];
    v.x = a.x + s * g.x + tv.x; v.y = a.y + s * g.y + tv.y;
    v.z = a.z + s * g.z + tv.z; v.w = a.w + s * g.w + tv.w;
  } else {
    v = reinterpret_cast<const float4*>(x + ((size_t)b * N0_ + (n - T_)) * C_)[c4];
  }
  reinterpret_cast<float4*>(xcat + (size_t)row * C_)[c4] = v;
}

// ---------------- LayerNorm (wave per row) -> bf16 ----------------
__global__ void k_ln(const float* __restrict__ xin, const float* __restrict__ g,
                     const float* __restrict__ bb, u16* __restrict__ hout) {
  int lane = threadIdx.x & 63, wid = threadIdx.x >> 6;
  int row = blockIdx.x * 4 + wid;
  const float4* xr = reinterpret_cast<const float4*>(xin + (size_t)row * C_);
  float4 v[3]; float s = 0.f, sq = 0.f;
#pragma unroll
  for (int c = 0; c < 3; ++c) {
    v[c] = xr[c * 64 + lane];
    s  += v[c].x + v[c].y + v[c].z + v[c].w;
    sq += v[c].x * v[c].x + v[c].y * v[c].y + v[c].z * v[c].z + v[c].w * v[c].w;
  }
#pragma unroll
  for (int m = 1; m < 64; m <<= 1) { s += __shfl_xor(s, m, 64); sq += __shfl_xor(sq, m, 64); }
  float mean = s * (1.f / C_);
  float rstd = rsqrtf(sq * (1.f / C_) - mean * mean + 1e-5f);
  ushort4* orow = reinterpret_cast<ushort4*>(hout + (size_t)row * C_);
#pragma unroll
  for (int c = 0; c < 3; ++c) {
    float4 gv = reinterpret_cast<const float4*>(g)[c * 64 + lane];
    float4 bv = reinterpret_cast<const float4*>(bb)[c * 64 + lane];
    ushort4 o;
    o.x = f2bf((v[c].x - mean) * rstd * gv.x + bv.x);
    o.y = f2bf((v[c].y - mean) * rstd * gv.y + bv.y);
    o.z = f2bf((v[c].z - mean) * rstd * gv.z + bv.z);
    o.w = f2bf((v[c].w - mean) * rstd * gv.w + bv.w);
    orow[c * 64 + lane] = o;
  }
}

// ---------------- GEMM: out[M,N] = A[M,K] * Bw[N,K]^T ----------------
// BMxBN tile, BK=64, 8 waves (2x4), dynamic LDS double-buffer, 2-phase
// prefetch (STAGE next tile before compute, ONE barrier+drain per tile),
// bijective XCD swizzle, XOR-swizzled LDS, global_load_lds w=16.
// EPI 0: qkv -> bf16 + scattered vT copy;  EPI 1: +bias+resid -> fp32;
// EPI 2: +bias, exact GELU -> bf16.
template<int EPI, int NDIM, int KDIM, int BM, int BN>
__global__ __launch_bounds__(512, 2) void k_gemm(
    const u16* __restrict__ A, const u16* __restrict__ Bw,
    u16* __restrict__ outb, float* __restrict__ outf,
    const float* __restrict__ bias, const float* __restrict__ resid,
    u16* __restrict__ vT) {
  extern __shared__ __align__(16) char smem[];
  constexpr int NMB  = (M_ + BM - 1) / BM;     // 66
  constexpr int MI   = BM / 32;                // M fragments per wave
  constexpr int NJ   = BN / 64;                // N fragments per wave
  constexpr int BUFB = (BM + BN) * 128;        // bytes per LDS buffer
  constexpr int NT   = KDIM / 64;

  const int lane = threadIdx.x & 63, wid = threadIdx.x >> 6;
  const int wr = wid >> 2, wc = wid & 3;

  // bijective XCD swizzle (m204 form; valid for any nwg)
  const int nwg = gridDim.x;
  const int q = nwg >> 3, r = nwg & 7;
  const int xcd = blockIdx.x & 7, sub = blockIdx.x >> 3;
  const int wgid = (xcd < r ? xcd * (q + 1) : r * (q + 1) + (xcd - r) * q) + sub;
  const int nb = wgid / NMB, mb = wgid - nb * NMB;
  const int m0 = mb * BM, n0 = nb * BN;

  auto stage = [&](int buf, int k0) {
    char* la = smem + buf * BUFB;
    char* lb = la + BM * 128;
#pragma unroll
    for (int jj = 0; jj < BM / 64; ++jj) {
      int j = jj * 8 + wid;
      int row = j * 8 + (lane >> 3);
      int gm = m0 + row; if (gm > M_ - 1) gm = M_ - 1;
      int cb = ((lane & 7) * 16) ^ ((row & 7) << 4);
      async_ld16((const char*)A + ((size_t)gm * KDIM + k0) * 2 + cb, la + j * 1024);
    }
#pragma unroll
    for (int jj = 0; jj < BN / 64; ++jj) {
      int j = jj * 8 + wid;
      int row = j * 8 + (lane >> 3);
      int cb = ((lane & 7) * 16) ^ ((row & 7) << 4);
      async_ld16((const char*)Bw + ((size_t)(n0 + row) * KDIM + k0) * 2 + cb,
                 lb + j * 1024);
    }
  };

  f32x4 acc[MI][NJ] = {};
  stage(0, 0);
  __syncthreads();                         // drain prologue staging
  int cur = 0;
#pragma unroll 1
  for (int t = 0; t < NT; ++t) {
    if (t + 1 < NT) stage(cur ^ 1, (t + 1) * 64);   // issue next tile early
    const char* la = smem + cur * BUFB;
    const char* lb = la + BM * 128;
#pragma unroll
    for (int kk = 0; kk < 2; ++kk) {
      s16x8 af[MI], bfr[NJ];
#pragma unroll
      for (int ii = 0; ii < MI; ++ii) {
        int row = wr * (BM / 2) + ii * 16 + (lane & 15);
        int cb = (kk * 64 + (lane >> 4) * 16) ^ ((row & 7) << 4);
        af[ii] = *reinterpret_cast<const s16x8*>(la + row * 128 + cb);
      }
#pragma unroll
      for (int jj = 0; jj < NJ; ++jj) {
        int row = wc * (BN / 4) + jj * 16 + (lane & 15);
        int cb = (kk * 64 + (lane >> 4) * 16) ^ ((row & 7) << 4);
        bfr[jj] = *reinterpret_cast<const s16x8*>(lb + row * 128 + cb);
      }
#pragma unroll
      for (int ii = 0; ii < MI; ++ii)
#pragma unroll
        for (int jj = 0; jj < NJ; ++jj)
          acc[ii][jj] = mfma16(af[ii], bfr[jj], acc[ii][jj]);
    }
    __syncthreads();                       // drains prefetch vmcnt + protects bufs
    cur ^= 1;
  }

  // epilogue: C/D layout col=lane&15, row=(lane>>4)*4+reg
#pragma unroll
  for (int ii = 0; ii < MI; ++ii) {
#pragma unroll
    for (int jj = 0; jj < NJ; ++jj) {
#pragma unroll
      for (int rr = 0; rr < 4; ++rr) {
        int gm = m0 + wr * (BM / 2) + ii * 16 + (lane >> 4) * 4 + rr;
        int gn = n0 + wc * (BN / 4) + jj * 16 + (lane & 15);
        if (gm < M_) {
          float v = acc[ii][jj][rr];
          if constexpr (EPI == 0) {
            u16 bv = f2bf(v);
            outb[(size_t)gm * NDIM + gn] = bv;
            if (gn >= 2 * C_) {                     // V part -> transposed copy
              int hh = (gn - 2 * C_) >> 6;
              int dh = gn & 63;
              int b2 = gm / NSEQ, nn = gm - b2 * NSEQ;
              vT[((size_t)(b2 * H_ + hh) * 64 + dh) * NPAD + nn] = bv;
            }
          } else if constexpr (EPI == 1) {
            size_t idx = (size_t)gm * NDIM + gn;
            outf[idx] = v + bias[gn] + resid[idx];
          } else {
            float t = v + bias[gn];
            outb[(size_t)gm * NDIM + gn] =
                f2bf(0.5f * t * (1.f + erff(t * 0.70710678118654752f)));
          }
        }
      }
    }
  }
}

// ---------------- flash attention (unchanged) ----------------
__global__ __launch_bounds__(256) void k_attn(const u16* __restrict__ qkv,
                                              const u16* __restrict__ vT,
                                              u16* __restrict__ o) {
  __shared__ __align__(16) char lds[24576];   // K 8K | Vt 8K | P 4x2K
  const int qt = blockIdx.x, bh = blockIdx.y;
  const int b = bh / H_, h = bh - b * H_;
  const int lane = threadIdx.x & 63, wid = threadIdx.x >> 6;

  s16x8 qf[2];
  {
    int n = qt * 64 + wid * 16 + (lane & 15); if (n > NSEQ - 1) n = NSEQ - 1;
    const u16* qrow = qkv + (size_t)(b * NSEQ + n) * (3 * C_) + h * 64 + (lane >> 4) * 8;
    qf[0] = *reinterpret_cast<const s16x8*>(qrow);
    qf[1] = *reinterpret_cast<const s16x8*>(qrow + 32);
  }
  float m_run[4] = {-1e30f, -1e30f, -1e30f, -1e30f};
  float l_run[4] = {0.f, 0.f, 0.f, 0.f};
  f32x4 oacc[4] = {};
  char* pl = lds + 16384 + wid * 2048;

  for (int t = 0; t < 9; ++t) {
    const int kv0 = t * 64;
    __syncthreads();
#pragma unroll
    for (int jj = 0; jj < 2; ++jj) {          // stage K tile [64 kv][64 dh]
      int j = wid * 2 + jj;
      int row = j * 8 + (lane >> 3);
      int n = kv0 + row; if (n > NSEQ - 1) n = NSEQ - 1;
      int cb = ((lane & 7) * 16) ^ ((row & 7) << 4);
      async_ld16((const char*)(qkv + (size_t)(b * NSEQ + n) * (3 * C_) + C_ + h * 64) + cb,
                 lds + j * 1024);
    }
#pragma unroll
    for (int jj = 0; jj < 2; ++jj) {          // stage Vt tile [64 dh][64 kv]
      int j = wid * 2 + jj;
      int dh = j * 8 + (lane >> 3);
      int cb = ((lane & 7) * 16) ^ ((dh & 7) << 4);
      async_ld16((const char*)(vT + ((size_t)bh * 64 + dh) * NPAD + kv0) + cb,
                 lds + 8192 + j * 1024);
    }
    __syncthreads();

    f32x4 sfr[4] = {};
#pragma unroll
    for (int kk = 0; kk < 2; ++kk) {
#pragma unroll
      for (int fc = 0; fc < 4; ++fc) {
        int row = fc * 16 + (lane & 15);
        int cb = (kk * 64 + (lane >> 4) * 16) ^ ((row & 7) << 4);
        s16x8 kf = *reinterpret_cast<const s16x8*>(lds + row * 128 + cb);
        sfr[fc] = mfma16(qf[kk], kf, sfr[fc]);
      }
    }
#pragma unroll
    for (int fc = 0; fc < 4; ++fc) {          // scale + tail mask BEFORE max
      bool valid = (kv0 + fc * 16 + (lane & 15)) < NSEQ;
#pragma unroll
      for (int rr = 0; rr < 4; ++rr)
        sfr[fc][rr] = valid ? sfr[fc][rr] * SCALE_ : -1e30f;
    }
#pragma unroll
    for (int rr = 0; rr < 4; ++rr) {          // online softmax per q row
      float mx = fmaxf(fmaxf(sfr[0][rr], sfr[1][rr]), fmaxf(sfr[2][rr], sfr[3][rr]));
      mx = fmaxf(mx, __shfl_xor(mx, 1, 64));
      mx = fmaxf(mx, __shfl_xor(mx, 2, 64));
      mx = fmaxf(mx, __shfl_xor(mx, 4, 64));
      mx = fmaxf(mx, __shfl_xor(mx, 8, 64));
      float mnew = fmaxf(m_run[rr], mx);
      float sc = __expf(m_run[rr] - mnew);
      l_run[rr] *= sc;
#pragma unroll
      for (int f2 = 0; f2 < 4; ++f2) oacc[f2][rr] *= sc;
      float ps = 0.f;
#pragma unroll
      for (int fc = 0; fc < 4; ++fc) {
        float p = __expf(sfr[fc][rr] - mnew);
        sfr[fc][rr] = p; ps += p;
      }
      ps += __shfl_xor(ps, 1, 64);
      ps += __shfl_xor(ps, 2, 64);
      ps += __shfl_xor(ps, 4, 64);
      ps += __shfl_xor(ps, 8, 64);
      l_run[rr] += ps;
      m_run[rr] = mnew;
    }
    // P: C/D layout -> per-wave LDS (swizzled) -> A-fragment layout
#pragma unroll
    for (int fc = 0; fc < 4; ++fc)
#pragma unroll
      for (int rr = 0; rr < 4; ++rr) {
        int row = (lane >> 4) * 4 + rr;
        int cb = ((fc * 16 + (lane & 15)) * 2) ^ ((row & 7) << 4);
        *reinterpret_cast<u16*>(pl + row * 128 + cb) = f2bf(sfr[fc][rr]);
      }
    s16x8 pf[2];
#pragma unroll
    for (int ks = 0; ks < 2; ++ks) {
      int row = lane & 15;
      int cb = (ks * 64 + (lane >> 4) * 16) ^ ((row & 7) << 4);
      pf[ks] = *reinterpret_cast<const s16x8*>(pl + row * 128 + cb);
    }
#pragma unroll
    for (int f2 = 0; f2 < 4; ++f2)
#pragma unroll
      for (int ks = 0; ks < 2; ++ks) {
        int vrow = f2 * 16 + (lane & 15);
        int cb = (ks * 64 + (lane >> 4) * 16) ^ ((vrow & 7) << 4);
        s16x8 vf = *reinterpret_cast<const s16x8*>(lds + 8192 + vrow * 128 + cb);
        oacc[f2] = mfma16(pf[ks], vf, oacc[f2]);
      }
  }
#pragma unroll
  for (int f2 = 0; f2 < 4; ++f2)
#pragma unroll
    for (int rr = 0; rr < 4; ++rr) {
      int n = qt * 64 + wid * 16 + (lane >> 4) * 4 + rr;
      if (n < NSEQ) {
        float val = oacc[f2][rr] / l_run[rr];
        o[(size_t)(b * NSEQ + n) * C_ + h * 64 + f2 * 16 + (lane & 15)] = f2bf(val);
      }
    }
}

extern "C" void kernel_launch(void* const* d_in, const int* in_sizes, int n_in,
                              void* d_out, int out_size, void* d_ws, size_t ws_size,
                              hipStream_t stream) {
  const float* x    = (const float*)d_in[0];
  const float* gf   = (const float*)d_in[1];
  const float* tp   = (const float*)d_in[2];
  const float* pe   = (const float*)d_in[3];
  const float* s1   = (const float*)d_in[4];
  const float* g1   = (const float*)d_in[5];
  const float* b1   = (const float*)d_in[6];
  const float* wqkv = (const float*)d_in[7];
  const float* wproj= (const float*)d_in[8];
  const float* bproj= (const float*)d_in[9];
  const float* g2   = (const float*)d_in[10];
  const float* b2   = (const float*)d_in[11];
  const float* wfc1 = (const float*)d_in[12];
  const float* bfc1 = (const float*)d_in[13];
  const float* wfc2 = (const float*)d_in[14];
  const float* bfc2 = (const float*)d_in[15];

  char* ws = (char*)d_ws;
  u16* h    = (u16*)ws;
  u16* qkvb = (u16*)(ws + OFF_A);
  u16* hmid = qkvb;                       // reuse after attention (spills into dead vT)
  u16* vTb  = (u16*)(ws + OFF_VT);
  u16* ob   = (u16*)(ws + OFF_O);
  u16* wqb  = (u16*)(ws + OFF_WQ);
  u16* wpb  = (u16*)(ws + OFF_WP);
  u16* w1b  = (u16*)(ws + OFF_W1);
  u16* w2b  = (u16*)(ws + OFF_W2);
  float* xcat = (float*)d_out;            // fp32 residual lives in d_out

  // allow >64KB dynamic LDS (idempotent, host-side, not a stream op)
  constexpr int SH256 = (256 + 256) * 128 * 2;   // 131072
  constexpr int SH128 = (256 + 128) * 128 * 2;   // 98304
  (void)hipFuncSetAttribute((const void*)&k_gemm<0, 2304, 768, 256, 256>,
      hipFuncAttributeMaxDynamicSharedMemorySize, SH256);
  (void)hipFuncSetAttribute((const void*)&k_gemm<2, 3072, 768, 256, 256>,
      hipFuncAttributeMaxDynamicSharedMemorySize, SH256);
  (void)hipFuncSetAttribute((const void*)&k_gemm<1, 768, 768, 256, 128>,
      hipFuncAttributeMaxDynamicSharedMemorySize, SH128);
  (void)hipFuncSetAttribute((const void*)&k_gemm<1, 768, 3072, 256, 128>,
      hipFuncAttributeMaxDynamicSharedMemorySize, SH128);

  k_cvt<<<(442368 + 255) / 256, 256, 0, stream>>>(wqkv, wqb, 442368);
  k_cvt<<<(147456 + 255) / 256, 256, 0, stream>>>(wproj, wpb, 147456);
  k_cvt<<<(589824 + 255) / 256, 256, 0, stream>>>(wfc1, w1b, 589824);
  k_cvt<<<(589824 + 255) / 256, 256, 0, stream>>>(wfc2, w2b, 589824);

  k_build<<<(M_ * C_ / 4 + 255) / 256, 256, 0, stream>>>(x, gf, tp, pe, s1, xcat);
  k_ln<<<M_ / 4, 256, 0, stream>>>(xcat, g1, b1, h);
  k_gemm<0, 2304, 768, 256, 256><<<66 * 9, 512, SH256, stream>>>(
      h, wqb, qkvb, nullptr, nullptr, nullptr, vTb);
  k_attn<<<dim3(9, B_ * H_), 256, 0, stream>>>(qkvb, vTb, ob);
  k_gemm<1, 768, 768, 256, 128><<<66 * 6, 512, SH128, stream>>>(
      ob, wpb, nullptr, xcat, bproj, xcat, nullptr);
  k_ln<<<M_ / 4, 256, 0, stream>>>(xcat, g2, b2, h);
  k_gemm<2, 3072, 768, 256, 256><<<66 * 12, 512, SH256, stream>>>(
      h, w1b, hmid, nullptr, bfc1, nullptr, nullptr);
  k_gemm<1, 768, 3072, 256, 128><<<66 * 6, 512, SH128, stream>>>(
      hmid, w2b, nullptr, (float*)d_out, bfc2, xcat, nullptr);
}